// Round 12
// baseline (47.235 us; speedup 1.0000x reference)
//
#include <hip/hip_runtime.h>
#include <math.h>

// B=4, C=64, H=W=128, OUTC=64, KS=3, taps N=9, K = 9*64 = 576. All fp16 data, f32 accum.
// ws layout (bytes):
//   x_t   fp16 [4][128][128][64]   @ 0        (8 MB) NHWC
//   cwtf  fp16 [9][2][4][64][8]    @ 8388608  (72 KB) main-conv B-fragments
//   pwtf  fp16 [9][2][2][64][8]    @ 8462336  (36 KB) offset-conv B-fragments (rows>=18 zero)
//   geomG u32  [1024][9][64][4]    @ 8499200  (9.4 MB) packed corner geometry
//   flagG int  [1024]              @ 17936384 (4 KB) per-block out-of-tile flag
#define CWTF_OFF 8388608
#define PWTF_OFF (CWTF_OFF + 73728)
#define GEOM_OFF (PWTF_OFF + 36864)
#define FLAG_OFF (GEOM_OFF + 9437184)

typedef __attribute__((ext_vector_type(8))) _Float16 half8;
typedef __attribute__((ext_vector_type(8))) unsigned short ushort8;
typedef __attribute__((ext_vector_type(4))) float f32x4;
typedef __attribute__((ext_vector_type(4))) unsigned int u32x4;

__device__ inline unsigned short f2h(float f) {
    _Float16 h = (_Float16)f; return __builtin_bit_cast(unsigned short, h);
}

// ---------------- prep: x NCHW f32 -> NHWC fp16, + weights -> fragment order ----------------
__global__ __launch_bounds__(256) void k_prep(const float* __restrict__ x,
                                              unsigned int* __restrict__ x_t_u32,
                                              const float* __restrict__ conv_w,
                                              const float* __restrict__ p_w,
                                              unsigned short* __restrict__ cwtf,
                                              unsigned short* __restrict__ pwtf) {
    if (blockIdx.x < 512) {
        __shared__ float t[64][129];
        int b = blockIdx.x >> 7;
        int i = blockIdx.x & 127;
        for (int idx = threadIdx.x; idx < 64 * 128; idx += 256) {
            int c = idx >> 7, j = idx & 127;
            t[c][j] = x[(((size_t)(b * 64 + c) * 128 + i) << 7) + j];
        }
        __syncthreads();
        unsigned int* dst = x_t_u32 + ((size_t)(b * 128 + i)) * 128 * 32;
        for (int idx2 = threadIdx.x; idx2 < 4096; idx2 += 256) {
            int j = idx2 >> 5, c2 = idx2 & 31;
            unsigned int lo = f2h(t[2 * c2][j]);
            unsigned int hi = f2h(t[2 * c2 + 1][j]);
            dst[idx2] = lo | (hi << 16);
        }
    } else {
        int tid = (blockIdx.x - 512) * 256 + threadIdx.x;
        if (tid < 36864) {
            int e = tid & 7, lane = (tid >> 3) & 63, nb = (tid >> 9) & 3, h = (tid >> 11) & 1, n = tid >> 12;
            int o = nb * 16 + (lane & 15);
            int c = h * 32 + ((lane >> 4) << 3) + e;
            cwtf[tid] = f2h(conv_w[(o * 64 + c) * 9 + n]);
        } else if (tid < 36864 + 18432) {
            int t2 = tid - 36864;
            int e = t2 & 7, lane = (t2 >> 3) & 63, nb = (t2 >> 9) & 1, h = (t2 >> 10) & 1, n = t2 >> 11;
            int np = nb * 16 + (lane & 15);
            int c = h * 32 + ((lane >> 4) << 3) + e;
            pwtf[t2] = (np < 18) ? f2h(p_w[(np * 64 + c) * 9 + n]) : (unsigned short)0;
        }
    }
}

// Main-conv tile geometry (k_off encodes against this, k_main stages it)
#define TROWS 7
#define TCOLS 71
#define TRECS (TROWS * TCOLS)      // 497 records of 128 B
#define TILE_B (TRECS * 128)       // 63616 B

// ---------------- k_off: offset conv + geometry (high occupancy, short blocks) ----------------
// Block = 64 pixels, 256 thr (4 waves). Wave wv = pixel group (16 px), FULL K per wave.
// Subtile margin 1: 3 rows x 66 cols = 25.3 KB. LDS total ~30 KB -> 5 blocks/CU.
#define SROWS 3
#define SCOLS 66
#define SRECS (SROWS * SCOLS)      // 198
__global__ __launch_bounds__(256, 4) void k_off(const unsigned short* __restrict__ x_t,
                                                const unsigned short* __restrict__ pwtf,
                                                const float* __restrict__ p_b,
                                                unsigned int* __restrict__ geomG,
                                                int* __restrict__ flagG) {
    __shared__ __align__(16) unsigned char S[SRECS * 128 + 4608 + 16];
    unsigned char* tile = S;
    float* offs = (float*)(S + SRECS * 128);
    int* flagp = (int*)(S + SRECS * 128 + 4608);

    int bid0 = blockIdx.x;
    int bid = (bid0 & 7) * 128 + (bid0 >> 3);  // chunked XCD swizzle (1024 % 8 == 0)
    int b = bid >> 8;
    int i = (bid >> 1) & 127;
    int j0 = (bid & 1) << 6;

    int tid = threadIdx.x;
    int lane = tid & 63;
    int r15 = lane & 15;
    int g = lane >> 4;
    int pg = tid >> 6;
    int pl = pg * 16 + r15;

    if (tid == 0) *flagp = 0;

    // stage margin-1 subtile (swizzled ds_write)
    for (int u = tid; u < SRECS * 8; u += 256) {
        int rec = u >> 3, chunk = u & 7;
        int trow = rec / SCOLS;
        int tcol = rec - trow * SCOLS;
        int gr = i - 1 + trow, gc = j0 - 1 + tcol;
        bool v = ((unsigned)gr < 128u) && ((unsigned)gc < 128u);
        int grc = v ? gr : 0, gcc = v ? gc : 0;
        ushort8 val = *(const ushort8*)(x_t + (((size_t)((b * 128 + grc) * 128 + gcc)) << 6) + (chunk << 3));
        if (!v) val = (ushort8)(unsigned short)0;
        *(ushort8*)(tile + rec * 128 + ((chunk ^ (rec & 7)) << 4)) = val;
    }
    __syncthreads();

    // offset conv: full K per wave (h0 + h1 chunks), no cross-wave reduce
    f32x4 aco0 = (f32x4)0.f, aco1 = (f32x4)0.f;
    for (int n = 0; n < 9; ++n) {
        int trec = (n / 3) * SCOLS + (pl + n % 3);
        int xb = trec & 7;
        half8 a0 = *(const half8*)(tile + trec * 128 + ((g ^ xb) << 4));
        half8 a1 = *(const half8*)(tile + trec * 128 + (((g + 4) ^ xb) << 4));
        const unsigned short* pb0 = pwtf + (((n * 2 + 0) * 2) << 9) + (lane << 3);
        const unsigned short* pb1 = pwtf + (((n * 2 + 1) * 2) << 9) + (lane << 3);
        aco0 = __builtin_amdgcn_mfma_f32_16x16x32_f16(a0, *(const half8*)pb0, aco0, 0, 0, 0);
        aco1 = __builtin_amdgcn_mfma_f32_16x16x32_f16(a0, *(const half8*)(pb0 + 512), aco1, 0, 0, 0);
        aco0 = __builtin_amdgcn_mfma_f32_16x16x32_f16(a1, *(const half8*)pb1, aco0, 0, 0, 0);
        aco1 = __builtin_amdgcn_mfma_f32_16x16x32_f16(a1, *(const half8*)(pb1 + 512), aco1, 0, 0, 0);
    }
#pragma unroll
    for (int rr = 0; rr < 4; ++rr) {
        int pix = pg * 16 + g * 4 + rr;
        offs[pix * 18 + r15] = aco0[rr] + p_b[r15];
        if (r15 < 2) offs[pix * 18 + 16 + r15] = aco1[rr] + p_b[16 + r15];
    }
    __syncthreads();

    // geometry -> geomG (coalesced: consecutive tid = consecutive pixel at same tap)
    int ib = i - 3, jb = j0 - 3;
    for (int t = tid; t < 576; t += 256) {
        int n = t >> 6, p = t & 63;
        float ox = offs[p * 18 + n];
        float oy = offs[p * 18 + 9 + n];
        float px = ox + (float)(i + 1) + (float)(n / 3 - 1);
        float py = oy + (float)(j0 + p + 1) + (float)(n % 3 - 1);
        float fx = floorf(px), fy = floorf(py);
        float qlx = fminf(fmaxf(fx, 0.f), 129.f);
        float qrx = fminf(fmaxf(fx + 1.f, 0.f), 129.f);
        float qly = fminf(fmaxf(fy, 0.f), 129.f);
        float qry = fminf(fmaxf(fy + 1.f, 0.f), 129.f);
        float pxc = fminf(fmaxf(px, 0.f), 129.f);
        float pyc = fminf(fmaxf(py, 0.f), 129.f);
        float ax = 1.f + qlx - pxc;
        float bx = 1.f - qrx + pxc;
        float ay = 1.f + qly - pyc;
        float by = 1.f - qry + pyc;
        int rlx = (int)qlx - 1, rrx = (int)qrx - 1;
        int rly = (int)qly - 1, rry = (int)qry - 1;
        bool bad = false;
        unsigned int pk[4];
        int cx[4] = {rlx, rrx, rlx, rrx};
        int cy[4] = {rly, rry, rry, rly};
        float cw[4] = {ax * ay, bx * by, ax * by, bx * ay};
#pragma unroll
        for (int k = 0; k < 4; ++k) {
            bool v = ((unsigned)cx[k] < 128u) && ((unsigned)cy[k] < 128u);
            bool intile = (((unsigned)(cx[k] - ib) < (unsigned)TROWS) &&
                           ((unsigned)(cy[k] - jb) < (unsigned)TCOLS));
            pk[k] = v ? (0x80000000u | ((unsigned)cx[k] << 23) | ((unsigned)cy[k] << 16) | f2h(cw[k])) : 0u;
            bad = bad || (v && !intile);
        }
        *(u32x4*)(geomG + (((size_t)bid * 9 + n) * 64 + p) * 4) = (u32x4){pk[0], pk[1], pk[2], pk[3]};
        if (bad) *flagp = 1;
    }
    __syncthreads();
    if (tid == 0) flagG[bid] = *flagp;
}

// ---------------- k_main: tile stage || geom prefetch -> sample+GEMM -> epilogue ----------------
// Block = 64 pixels, 8 waves (512 thr): wave wv = (pg = wv&3, h = wv>>2). 3 barriers total.
__global__ __launch_bounds__(512, 2) void k_main(const unsigned short* __restrict__ x_t,
                                                 const unsigned short* __restrict__ cwtf,
                                                 const float* __restrict__ conv_b,
                                                 const unsigned int* __restrict__ geomG,
                                                 const int* __restrict__ flagG,
                                                 float* __restrict__ out) {
    __shared__ __align__(16) unsigned char S[TILE_B + 16];
    unsigned char* tile = S;

    int bid0 = blockIdx.x;
    int bid = (bid0 & 7) * 128 + (bid0 >> 3);
    int b = bid >> 8;
    int i = (bid >> 1) & 127;
    int j0 = (bid & 1) << 6;
    int ib = i - 3, jb = j0 - 3;

    int tid = threadIdx.x;
    int lane = tid & 63;
    int r15 = lane & 15;
    int g = lane >> 4;
    int wv = tid >> 6;
    int pg = wv & 3;
    int h = wv >> 2;
    int pl = pg * 16 + r15;
    int cs = g + (h << 2);

    // prefetch geometry + flag (independent of tile staging; overlaps)
    int flag = flagG[bid];
    u32x4 gq[9];
#pragma unroll
    for (int n = 0; n < 9; ++n)
        gq[n] = *(const u32x4*)(geomG + (((size_t)bid * 9 + n) * 64 + pl) * 4);

    // stage margin-3 tile (swizzled ds_write)
    for (int u = tid; u < TRECS * 8; u += 512) {
        int rec = u >> 3, chunk = u & 7;
        int trow = rec / TCOLS;
        int tcol = rec - trow * TCOLS;
        int gr = ib + trow, gc = jb + tcol;
        bool v = ((unsigned)gr < 128u) && ((unsigned)gc < 128u);
        int grc = v ? gr : 0, gcc = v ? gc : 0;
        ushort8 val = *(const ushort8*)(x_t + (((size_t)((b * 128 + grc) * 128 + gcc)) << 6) + (chunk << 3));
        if (!v) val = (ushort8)(unsigned short)0;
        *(ushort8*)(tile + rec * 128 + ((chunk ^ (rec & 7)) << 4)) = val;
    }
    __syncthreads();

    // sample + GEMM
    f32x4 acc[4];
#pragma unroll
    for (int nb = 0; nb < 4; ++nb) acc[nb] = (f32x4)0.f;

    if (flag == 0) {
        for (int n = 0; n < 9; ++n) {
            half8 Bf[4];
#pragma unroll
            for (int nb = 0; nb < 4; ++nb)
                Bf[nb] = *(const half8*)(cwtf + ((((n * 2 + h) << 2) + nb) << 9) + (lane << 3));
            half8 av = (half8)(_Float16)0;
#pragma unroll
            for (int k = 0; k < 4; ++k) {
                unsigned int p = gq[n][k];
                int rx = (int)((p >> 23) & 127u), ry = (int)((p >> 16) & 127u);
                int trec = (rx - ib) * TCOLS + (ry - jb);
                if (p == 0u) trec = 0;
                _Float16 wk = __builtin_bit_cast(_Float16, (unsigned short)(p & 0xFFFFu));
                int xb = trec & 7;
                half8 u = *(const half8*)(tile + trec * 128 + ((cs ^ xb) << 4));
                av += u * wk;
            }
#pragma unroll
            for (int nb = 0; nb < 4; ++nb)
                acc[nb] = __builtin_amdgcn_mfma_f32_16x16x32_f16(av, Bf[nb], acc[nb], 0, 0, 0);
        }
    } else {
        for (int n = 0; n < 9; ++n) {
            half8 Bf[4];
#pragma unroll
            for (int nb = 0; nb < 4; ++nb)
                Bf[nb] = *(const half8*)(cwtf + ((((n * 2 + h) << 2) + nb) << 9) + (lane << 3));
            half8 av = (half8)(_Float16)0;
#pragma unroll
            for (int k = 0; k < 4; ++k) {
                unsigned int p = gq[n][k];
                int rx = (int)((p >> 23) & 127u), ry = (int)((p >> 16) & 127u);
                size_t base = (p == 0u) ? 0 : (((size_t)((b * 128 + rx) * 128 + ry)) << 6);
                _Float16 wk = __builtin_bit_cast(_Float16, (unsigned short)(p & 0xFFFFu));
                half8 u = *(const half8*)(x_t + base + (cs << 3));
                av += u * wk;
            }
#pragma unroll
            for (int nb = 0; nb < 4; ++nb)
                acc[nb] = __builtin_amdgcn_mfma_f32_16x16x32_f16(av, Bf[nb], acc[nb], 0, 0, 0);
        }
    }
    __syncthreads();  // tile dead; reuse as ep0/ep1

    // epilogue: disjoint per-half regions, one barrier, summed at store
    {
        float* epH = (float*)(S + (h ? 16640 : 0));
#pragma unroll
        for (int nb = 0; nb < 4; ++nb) {
            int o = nb * 16 + r15;
#pragma unroll
            for (int rr = 0; rr < 4; ++rr) {
                int pix = pg * 16 + g * 4 + rr;
                epH[o * 65 + pix] = acc[nb][rr];
            }
        }
    }
    __syncthreads();
    {
        float* e0 = (float*)S;
        float* e1 = (float*)(S + 16640);
        for (int t = tid; t < 4096; t += 512) {
            int o = t >> 6;
            int p = t & 63;
            out[(((size_t)(b * 64 + o)) << 14) + (i << 7) + j0 + p] =
                e0[o * 65 + p] + e1[o * 65 + p] + conv_b[o];
        }
    }
}

extern "C" void kernel_launch(void* const* d_in, const int* in_sizes, int n_in,
                              void* d_out, int out_size, void* d_ws, size_t ws_size,
                              hipStream_t stream) {
    const float* x = (const float*)d_in[0];
    const float* p_w = (const float*)d_in[1];
    const float* p_b = (const float*)d_in[2];
    const float* conv_w = (const float*)d_in[3];
    const float* conv_b = (const float*)d_in[4];
    float* out = (float*)d_out;
    char* ws = (char*)d_ws;

    unsigned short* x_t = (unsigned short*)(ws);
    unsigned short* cwtf = (unsigned short*)(ws + CWTF_OFF);
    unsigned short* pwtf = (unsigned short*)(ws + PWTF_OFF);
    unsigned int* geomG = (unsigned int*)(ws + GEOM_OFF);
    int* flagG = (int*)(ws + FLAG_OFF);

    k_prep<<<728, 256, 0, stream>>>(x, (unsigned int*)x_t, conv_w, p_w, cwtf, pwtf);
    k_off<<<1024, 256, 0, stream>>>(x_t, pwtf, p_b, geomG, flagG);
    k_main<<<1024, 512, 0, stream>>>(x_t, cwtf, conv_b, geomG, flagG, out);
}

// Round 13
// 45.970 us; speedup vs baseline: 1.0275x; 1.0275x over previous
//
#include <hip/hip_runtime.h>
#include <math.h>

// B=4, C=64, H=W=128, OUTC=64, KS=3, taps N=9, K = 9*64 = 576. All fp16 data, f32 accum.
// ws layout (bytes):
//   x_t   fp16 [4][128][128][64]   @ 0        (8 MB) NHWC
//   cwtf  fp16 [9][2][4][64][8]    @ 8388608  (72 KB) main-conv B-fragments
//   pwtf  fp16 [9][2][2][64][8]    @ 8462336  (36 KB) offset-conv B-fragments (rows>=18 zero)
#define CWTF_OFF 8388608
#define PWTF_OFF (CWTF_OFF + 73728)

typedef __attribute__((ext_vector_type(8))) _Float16 half8;
typedef __attribute__((ext_vector_type(8))) unsigned short ushort8;
typedef __attribute__((ext_vector_type(4))) float f32x4;
typedef __attribute__((ext_vector_type(4))) unsigned int u32x4;

__device__ inline unsigned short f2h(float f) {
    _Float16 h = (_Float16)f; return __builtin_bit_cast(unsigned short, h);
}

// ---------------- prep: x NCHW f32 -> NHWC fp16, + weights -> fragment order ----------------
__global__ __launch_bounds__(256) void k_prep(const float* __restrict__ x,
                                              unsigned int* __restrict__ x_t_u32,
                                              const float* __restrict__ conv_w,
                                              const float* __restrict__ p_w,
                                              unsigned short* __restrict__ cwtf,
                                              unsigned short* __restrict__ pwtf) {
    if (blockIdx.x < 512) {
        __shared__ float t[64][129];
        int b = blockIdx.x >> 7;
        int i = blockIdx.x & 127;
        for (int idx = threadIdx.x; idx < 64 * 128; idx += 256) {
            int c = idx >> 7, j = idx & 127;
            t[c][j] = x[(((size_t)(b * 64 + c) * 128 + i) << 7) + j];
        }
        __syncthreads();
        unsigned int* dst = x_t_u32 + ((size_t)(b * 128 + i)) * 128 * 32;
        for (int idx2 = threadIdx.x; idx2 < 4096; idx2 += 256) {
            int j = idx2 >> 5, c2 = idx2 & 31;
            unsigned int lo = f2h(t[2 * c2][j]);
            unsigned int hi = f2h(t[2 * c2 + 1][j]);
            dst[idx2] = lo | (hi << 16);
        }
    } else {
        int tid = (blockIdx.x - 512) * 256 + threadIdx.x;
        if (tid < 36864) {
            int e = tid & 7, lane = (tid >> 3) & 63, nb = (tid >> 9) & 3, h = (tid >> 11) & 1, n = tid >> 12;
            int o = nb * 16 + (lane & 15);
            int c = h * 32 + ((lane >> 4) << 3) + e;
            cwtf[tid] = f2h(conv_w[(o * 64 + c) * 9 + n]);
        } else if (tid < 36864 + 18432) {
            int t2 = tid - 36864;
            int e = t2 & 7, lane = (t2 >> 3) & 63, nb = (t2 >> 9) & 1, h = (t2 >> 10) & 1, n = t2 >> 11;
            int np = nb * 16 + (lane & 15);
            int c = h * 32 + ((lane >> 4) << 3) + e;
            pwtf[t2] = (np < 18) ? f2h(p_w[(np * 64 + c) * 9 + n]) : (unsigned short)0;
        }
    }
}

// ---------------- fused kernel (r11 base, M-blocked: 4 waves, 32 px + 2 A-frags per wave) ----------------
// Block = 64 pixels (b, i, j0..j0+63), 4 waves (256 thr): wave wv = (pg = wv&1, h = wv>>1).
// Wave handles 32 pixels (A-frags pl0, pl0+16) and k-half h. Each B-fragment feeds 2 MFMAs.
// MFMA 16x16x32 f16: A m=lane&15, k=8*(lane>>4)+e; B n=lane&15 same k; D n=lane&15, m=4*(lane>>4)+reg.
#define TROWS 7
#define TCOLS 71
#define TRECS (TROWS * TCOLS)      // 497 records of 128 B (64 ch fp16)
#define TILE_B (TRECS * 128)       // 63616 B
#define OFF_OFFS TILE_B            // 4608 B  [64][18] f32
#define OFF_GEOM (TILE_B + 4608)   // 9216 B  [9][64][4] packed u32
#define OFF_FLAG (TILE_B + 4608 + 9216)
// Epilogue: ep0 @ 0, ep1 @ 16640 ([64][65] f32 each) overlay the dead tile.

__global__ __launch_bounds__(256, 2) void k_fused(const unsigned short* __restrict__ x_t,
                                                  const unsigned short* __restrict__ cwtf,
                                                  const unsigned short* __restrict__ pwtf,
                                                  const float* __restrict__ p_b,
                                                  const float* __restrict__ conv_b,
                                                  float* __restrict__ out) {
    __shared__ __align__(16) unsigned char S[TILE_B + 4608 + 9216 + 16];
    unsigned char* tile = S;
    float* offs = (float*)(S + OFF_OFFS);
    unsigned char* geomB = S + OFF_GEOM;
    int* flagp = (int*)(S + OFF_FLAG);

    int bid0 = blockIdx.x;
    int bid = (bid0 & 7) * 128 + (bid0 >> 3);  // chunked XCD swizzle (1024 % 8 == 0)
    int b = bid >> 8;
    int i = (bid >> 1) & 127;
    int j0 = (bid & 1) << 6;
    int ib = i - 3, jb = j0 - 3;

    int tid = threadIdx.x;
    int lane = tid & 63;
    int r15 = lane & 15;
    int g = lane >> 4;
    int wv = tid >> 6;
    int pg = wv & 1;             // 32-pixel group
    int h = wv >> 1;             // k-half
    int pl0 = pg * 32 + r15;     // A-frag 0 pixel
    int pl1 = pl0 + 16;          // A-frag 1 pixel
    int cs = g + (h << 2);       // chunk slot: channels cs*8..cs*8+7

    if (tid == 0) *flagp = 0;

    // ---- stage swizzled x-tile (coalesced global, swizzled ds_write) ----
    for (int u = tid; u < TRECS * 8; u += 256) {
        int rec = u >> 3, chunk = u & 7;
        int trow = rec / TCOLS;
        int tcol = rec - trow * TCOLS;
        int gr = ib + trow, gc = jb + tcol;
        bool v = ((unsigned)gr < 128u) && ((unsigned)gc < 128u);
        int grc = v ? gr : 0, gcc = v ? gc : 0;
        ushort8 val = *(const ushort8*)(x_t + (((size_t)((b * 128 + grc) * 128 + gcc)) << 6) + (chunk << 3));
        if (!v) val = (ushort8)(unsigned short)0;
        *(ushort8*)(tile + rec * 128 + ((chunk ^ (rec & 7)) << 4)) = val;
    }
    __syncthreads();

    // ---- phase 1: offset conv — 2 A-frags, B-frags reused across both ----
    f32x4 aco[2][2];
#pragma unroll
    for (int f = 0; f < 2; ++f)
#pragma unroll
        for (int nb = 0; nb < 2; ++nb) aco[f][nb] = (f32x4)0.f;

    for (int n = 0; n < 9; ++n) {
        int du = n / 3 - 1, dv = n % 3 - 1;
        int trec0 = (du + 3) * TCOLS + (pl0 + dv + 3);
        int trec1 = trec0 + 16;
        half8 a0 = *(const half8*)(tile + trec0 * 128 + ((cs ^ (trec0 & 7)) << 4));
        half8 a1 = *(const half8*)(tile + trec1 * 128 + ((cs ^ (trec1 & 7)) << 4));
        const unsigned short* pb = pwtf + (((n * 2 + h) * 2) << 9) + (lane << 3);
        half8 b0 = *(const half8*)pb;
        half8 b1 = *(const half8*)(pb + 512);
        aco[0][0] = __builtin_amdgcn_mfma_f32_16x16x32_f16(a0, b0, aco[0][0], 0, 0, 0);
        aco[0][1] = __builtin_amdgcn_mfma_f32_16x16x32_f16(a0, b1, aco[0][1], 0, 0, 0);
        aco[1][0] = __builtin_amdgcn_mfma_f32_16x16x32_f16(a1, b0, aco[1][0], 0, 0, 0);
        aco[1][1] = __builtin_amdgcn_mfma_f32_16x16x32_f16(a1, b1, aco[1][1], 0, 0, 0);
    }
    // cross-h reduction of offsets: h=0 writes (+bias), h=1 adds
#pragma unroll
    for (int hh = 0; hh < 2; ++hh) {
        if (h == hh) {
#pragma unroll
            for (int f = 0; f < 2; ++f) {
#pragma unroll
                for (int nb = 0; nb < 2; ++nb) {
                    int np = nb * 16 + r15;
                    if (np < 18) {
#pragma unroll
                        for (int rr = 0; rr < 4; ++rr) {
                            int pix = pg * 32 + f * 16 + g * 4 + rr;
                            if (hh == 0)
                                offs[pix * 18 + np] = aco[f][nb][rr] + p_b[np];
                            else
                                offs[pix * 18 + np] += aco[f][nb][rr];
                        }
                    }
                }
            }
        }
        __syncthreads();
    }

    // ---- phase 2: bilinear geometry, packed (validbit|rx|ry|f16 w) ----
    for (int t = tid; t < 576; t += 256) {
        int p = t / 9;
        int n = t - p * 9;
        float ox = offs[p * 18 + n];
        float oy = offs[p * 18 + 9 + n];
        float px = ox + (float)(i + 1) + (float)(n / 3 - 1);
        float py = oy + (float)(j0 + p + 1) + (float)(n % 3 - 1);
        float fx = floorf(px), fy = floorf(py);
        float qlx = fminf(fmaxf(fx, 0.f), 129.f);
        float qrx = fminf(fmaxf(fx + 1.f, 0.f), 129.f);
        float qly = fminf(fmaxf(fy, 0.f), 129.f);
        float qry = fminf(fmaxf(fy + 1.f, 0.f), 129.f);
        float pxc = fminf(fmaxf(px, 0.f), 129.f);
        float pyc = fminf(fmaxf(py, 0.f), 129.f);
        float ax = 1.f + qlx - pxc;
        float bx = 1.f - qrx + pxc;
        float ay = 1.f + qly - pyc;
        float by = 1.f - qry + pyc;
        int rlx = (int)qlx - 1, rrx = (int)qrx - 1;
        int rly = (int)qly - 1, rry = (int)qry - 1;
        bool bad = false;
        unsigned int pk[4];
        int cx[4] = {rlx, rrx, rlx, rrx};
        int cy[4] = {rly, rry, rry, rly};
        float cw[4] = {ax * ay, bx * by, ax * by, bx * ay};
#pragma unroll
        for (int k = 0; k < 4; ++k) {
            bool v = ((unsigned)cx[k] < 128u) && ((unsigned)cy[k] < 128u);
            bool intile = (((unsigned)(cx[k] - ib) < (unsigned)TROWS) &&
                           ((unsigned)(cy[k] - jb) < (unsigned)TCOLS));
            pk[k] = v ? (0x80000000u | ((unsigned)cx[k] << 23) | ((unsigned)cy[k] << 16) | f2h(cw[k])) : 0u;
            bad = bad || (v && !intile);
        }
        *(u32x4*)(geomB + ((n * 64 + p) << 4)) = (u32x4){pk[0], pk[1], pk[2], pk[3]};
        if (bad) *flagp = 1;
    }
    __syncthreads();

    // ---- phase 3: main conv — 2 A-frags per wave, B-frags reused across both ----
    f32x4 acc[2][4];
#pragma unroll
    for (int f = 0; f < 2; ++f)
#pragma unroll
        for (int nb = 0; nb < 4; ++nb) acc[f][nb] = (f32x4)0.f;
    bool fast = (*flagp == 0);

    if (fast) {
        for (int n = 0; n < 9; ++n) {
            u32x4 gq0 = *(const u32x4*)(geomB + ((n * 64 + pl0) << 4));
            u32x4 gq1 = *(const u32x4*)(geomB + ((n * 64 + pl1) << 4));
            half8 Bf[4];
#pragma unroll
            for (int nb = 0; nb < 4; ++nb)
                Bf[nb] = *(const half8*)(cwtf + ((((n * 2 + h) << 2) + nb) << 9) + (lane << 3));
            half8 av0 = (half8)(_Float16)0, av1 = (half8)(_Float16)0;
#pragma unroll
            for (int k = 0; k < 4; ++k) {
                unsigned int p0 = gq0[k];
                unsigned int p1 = gq1[k];
                int rx0 = (int)((p0 >> 23) & 127u), ry0 = (int)((p0 >> 16) & 127u);
                int rx1 = (int)((p1 >> 23) & 127u), ry1 = (int)((p1 >> 16) & 127u);
                int t0 = (rx0 - ib) * TCOLS + (ry0 - jb);
                int t1 = (rx1 - ib) * TCOLS + (ry1 - jb);
                if (p0 == 0u) t0 = 0;
                if (p1 == 0u) t1 = 0;
                _Float16 w0 = __builtin_bit_cast(_Float16, (unsigned short)(p0 & 0xFFFFu));
                _Float16 w1 = __builtin_bit_cast(_Float16, (unsigned short)(p1 & 0xFFFFu));
                half8 u0 = *(const half8*)(tile + t0 * 128 + ((cs ^ (t0 & 7)) << 4));
                half8 u1 = *(const half8*)(tile + t1 * 128 + ((cs ^ (t1 & 7)) << 4));
                av0 += u0 * w0;
                av1 += u1 * w1;
            }
#pragma unroll
            for (int nb = 0; nb < 4; ++nb) {
                acc[0][nb] = __builtin_amdgcn_mfma_f32_16x16x32_f16(av0, Bf[nb], acc[0][nb], 0, 0, 0);
                acc[1][nb] = __builtin_amdgcn_mfma_f32_16x16x32_f16(av1, Bf[nb], acc[1][nb], 0, 0, 0);
            }
        }
    } else {
        for (int n = 0; n < 9; ++n) {
            u32x4 gq0 = *(const u32x4*)(geomB + ((n * 64 + pl0) << 4));
            u32x4 gq1 = *(const u32x4*)(geomB + ((n * 64 + pl1) << 4));
            half8 Bf[4];
#pragma unroll
            for (int nb = 0; nb < 4; ++nb)
                Bf[nb] = *(const half8*)(cwtf + ((((n * 2 + h) << 2) + nb) << 9) + (lane << 3));
            half8 av0 = (half8)(_Float16)0, av1 = (half8)(_Float16)0;
#pragma unroll
            for (int k = 0; k < 4; ++k) {
                unsigned int p0 = gq0[k];
                unsigned int p1 = gq1[k];
                int rx0 = (int)((p0 >> 23) & 127u), ry0 = (int)((p0 >> 16) & 127u);
                int rx1 = (int)((p1 >> 23) & 127u), ry1 = (int)((p1 >> 16) & 127u);
                size_t b0a = (p0 == 0u) ? 0 : (((size_t)((b * 128 + rx0) * 128 + ry0)) << 6);
                size_t b1a = (p1 == 0u) ? 0 : (((size_t)((b * 128 + rx1) * 128 + ry1)) << 6);
                _Float16 w0 = __builtin_bit_cast(_Float16, (unsigned short)(p0 & 0xFFFFu));
                _Float16 w1 = __builtin_bit_cast(_Float16, (unsigned short)(p1 & 0xFFFFu));
                half8 u0 = *(const half8*)(x_t + b0a + (cs << 3));
                half8 u1 = *(const half8*)(x_t + b1a + (cs << 3));
                av0 += u0 * w0;
                av1 += u1 * w1;
            }
#pragma unroll
            for (int nb = 0; nb < 4; ++nb) {
                acc[0][nb] = __builtin_amdgcn_mfma_f32_16x16x32_f16(av0, Bf[nb], acc[0][nb], 0, 0, 0);
                acc[1][nb] = __builtin_amdgcn_mfma_f32_16x16x32_f16(av1, Bf[nb], acc[1][nb], 0, 0, 0);
            }
        }
    }
    __syncthreads();  // tile dead; reuse as ep0/ep1

    // ---- epilogue: disjoint per-half regions, ONE barrier, summed at store ----
    {
        float* epH = (float*)(S + (h ? 16640 : 0));
#pragma unroll
        for (int f = 0; f < 2; ++f) {
#pragma unroll
            for (int nb = 0; nb < 4; ++nb) {
                int o = nb * 16 + r15;
#pragma unroll
                for (int rr = 0; rr < 4; ++rr) {
                    int pix = pg * 32 + f * 16 + g * 4 + rr;
                    epH[o * 65 + pix] = acc[f][nb][rr];
                }
            }
        }
    }
    __syncthreads();
    {
        float* e0 = (float*)S;
        float* e1 = (float*)(S + 16640);
        for (int t = tid; t < 4096; t += 256) {
            int o = t >> 6;
            int p = t & 63;
            out[(((size_t)(b * 64 + o)) << 14) + (i << 7) + j0 + p] =
                e0[o * 65 + p] + e1[o * 65 + p] + conv_b[o];
        }
    }
}

extern "C" void kernel_launch(void* const* d_in, const int* in_sizes, int n_in,
                              void* d_out, int out_size, void* d_ws, size_t ws_size,
                              hipStream_t stream) {
    const float* x = (const float*)d_in[0];
    const float* p_w = (const float*)d_in[1];
    const float* p_b = (const float*)d_in[2];
    const float* conv_w = (const float*)d_in[3];
    const float* conv_b = (const float*)d_in[4];
    float* out = (float*)d_out;
    char* ws = (char*)d_ws;

    unsigned short* x_t = (unsigned short*)(ws);
    unsigned short* cwtf = (unsigned short*)(ws + CWTF_OFF);
    unsigned short* pwtf = (unsigned short*)(ws + PWTF_OFF);

    k_prep<<<728, 256, 0, stream>>>(x, (unsigned int*)x_t, conv_w, p_w, cwtf, pwtf);
    k_fused<<<1024, 256, 0, stream>>>(x_t, cwtf, pwtf, p_b, conv_b, out);
}